// Round 13
// baseline (23.633 us; speedup 1.0000x reference)
//
#include <hip/hip_runtime.h>
#include <math.h>

#define NPTS 4096
#define NB   8
#define QCB  512          // queries per block (16 waves x 32 rows)
#define RCB  512          // refs per block (16 tiles x 32)
#define NRT  16           // ref tiles per block

typedef _Float16 h8     __attribute__((ext_vector_type(8)));
typedef float    f32x16 __attribute__((ext_vector_type(16)));

__device__ __forceinline__ void split2(float v, _Float16& h, _Float16& l) {
    h = (_Float16)v;
    l = (_Float16)(v - (float)h);
}

// Init: fill qmin/rmin (2*NB*NPTS uints) with UINT_MAX, zero the counter.
__global__ __launch_bounds__(1024) void chamfer_init(unsigned* __restrict__ buf,
                                                     int* __restrict__ counter) {
    buf[blockIdx.x * 1024 + threadIdx.x] = 0xFFFFFFFFu;
    if (blockIdx.x == 0 && threadIdx.x == 0) *counter = 0;
}

// Stage 1: one block per (batch, q-chunk, r-chunk); d = pn+gn-2p.g via the
// R9-validated K=16 f16 hi/lo-split MFMA embedding (exact, absmax 0.0 x3).
// Row-min: LDS transpose, stride 34 (2-way conflicts only) + float2 reads.
// Col-min: R10-proven fminf tree + LDS int atomicMin. Both directions then
// combine globally via uint-punned atomicMin (values clamped >= 0).
__global__ __launch_bounds__(1024, 2) void chamfer_mfma32(
    const float* __restrict__ P, const float* __restrict__ G,
    unsigned* __restrict__ qmin,   // [NB][NPTS] p2g squared-NN (uint bits)
    unsigned* __restrict__ rmin)   // [NB][NPTS] g2p squared-NN
{
    __shared__ __align__(16) unsigned char smem[69632];
    h8*    Bfr  = (h8*)smem;                 // [0, 16384): 16 tiles x 64 entries
    int*   rbuf = (int*)(smem + 16384);      // [16384, 18432): 512 col-mins
    float* qtr  = (float*)smem;              // aliased in phase 3 only

    const int b    = blockIdx.y;
    const int qc   = blockIdx.x >> 3;   // 0..7
    const int rc   = blockIdx.x & 7;    // 0..7
    const int tid  = threadIdx.x;
    const int w    = tid >> 6;
    const int lane = tid & 63;
    const int col  = lane & 31;
    const int kg   = lane >> 5;

    const float* __restrict__ Pb = P + (size_t)b * NPTS * 3;
    const float* __restrict__ Gb = G + (size_t)b * NPTS * 3;

    const _Float16 one = (_Float16)1.f, zr = (_Float16)0.f;

    // ---- stage B-frags (1024 entries, 1/thread) + init rbuf
    if (tid < RCB) rbuf[tid] = 0x7f7fffff;   // FLT_MAX bits (values clamped >= 0)
    {
        const int el   = tid & 63;
        const int ecol = el & 31, ekg = el >> 5;
        const int ref  = rc * RCB + (tid >> 6) * 32 + ecol;
        const float gx = Gb[3 * ref], gy = Gb[3 * ref + 1], gz = Gb[3 * ref + 2];
        const float gn = fmaf(gx, gx, fmaf(gy, gy, gz * gz));
        _Float16 xh, xl, yh, yl, zh, zl, nh, nl;
        split2(gx, xh, xl); split2(gy, yh, yl); split2(gz, zh, zl); split2(gn, nh, nl);
        Bfr[tid] = ekg ? (h8){one, nh, xl, yl, zl, zr, nl, zr}
                       : (h8){xh, yh, zh, one, nh, xh, yh, zh};
    }

    // ---- A-frag (per lane, registers)
    const int q0 = qc * QCB + w * 32 + col;
    const float px = Pb[3 * q0], py = Pb[3 * q0 + 1], pz = Pb[3 * q0 + 2];
    const float m2x = -2.f * px, m2y = -2.f * py, m2z = -2.f * pz;
    const float pn = fmaf(px, px, fmaf(py, py, pz * pz));
    _Float16 axh, axl, ayh, ayl, azh, azl, aph, apl;
    split2(m2x, axh, axl); split2(m2y, ayh, ayl); split2(m2z, azh, azl); split2(pn, aph, apl);
    const h8 afr = kg ? (h8){apl, zr, axh, ayh, azh, aph, one, zr}
                      : (h8){axh, ayh, azh, aph, one, axl, ayl, azl};

    f32x16 qacc;
#pragma unroll
    for (int j = 0; j < 16; ++j) qacc[j] = 3.4e38f;

    __syncthreads();

    // ---- main loop: 16 MFMAs; row-min into regs, col-min tree -> LDS atomicMin
    const f32x16 cz = (f32x16){0.f,0.f,0.f,0.f,0.f,0.f,0.f,0.f,
                               0.f,0.f,0.f,0.f,0.f,0.f,0.f,0.f};
#pragma unroll
    for (int rt = 0; rt < NRT; ++rt) {
        const h8 bfr = Bfr[rt * 64 + lane];
        f32x16 d = __builtin_amdgcn_mfma_f32_32x32x16_f16(afr, bfr, cz, 0, 0, 0);
#pragma unroll
        for (int j = 0; j < 16; ++j) qacc[j] = fminf(qacc[j], d[j]);
        float t0 = fminf(fminf(d[0],  d[1]),  d[2]);
        float t1 = fminf(fminf(d[3],  d[4]),  d[5]);
        float t2 = fminf(fminf(d[6],  d[7]),  d[8]);
        float t3 = fminf(fminf(d[9],  d[10]), d[11]);
        float t4 = fminf(fminf(d[12], d[13]), d[14]);
        float v  = fminf(fminf(fminf(t0, t1), t2), fminf(fminf(t3, t4), d[15]));
        v = fmaxf(v, 0.f);
        atomicMin(&rbuf[rt * 32 + col], __float_as_int(v));
    }

    // ---- drain col-mins: 1 LDS read + 1 global atomicMin per ref
    __syncthreads();
    if (tid < RCB)
        atomicMin(&rmin[(size_t)b * NPTS + rc * RCB + tid], (unsigned)rbuf[tid]);
    __syncthreads();   // Bfr + rbuf dead; qtr may alias

    // ---- phase 3: row-min via per-wave LDS transpose, stride 34 (2-way only)
    float* qw = qtr + w * (32 * 34);           // 32 rows x 34 floats = 4352 B
#pragma unroll
    for (int j = 0; j < 16; ++j) {
        const int row = (j & 3) + 8 * (j >> 2) + 4 * kg;
        qw[row * 34 + col] = qacc[j];
    }
    // wave-private region: same wave writes then reads; lgkmcnt orders it
    if (lane < 32) {
        const float2* qr = (const float2*)(qw + lane * 34);
        float m = 3.4e38f;
#pragma unroll
        for (int k = 0; k < 16; ++k) {
            float2 u = qr[k];
            m = fminf(m, fminf(u.x, u.y));
        }
        atomicMin(&qmin[(size_t)b * NPTS + qc * QCB + w * 32 + lane],
                  __float_as_uint(fmaxf(m, 0.f)));
    }
}

// Stage 2: 64 blocks (path,b,sp); sum 1024 elems each -> sums[64];
// last block: 16 x sqrt(mean) -> 3 outputs. (R10-proven pattern.)
__global__ __launch_bounds__(256) void chamfer_reduce2(
    const unsigned* __restrict__ qmin, const unsigned* __restrict__ rmin,
    float* __restrict__ sums, int* __restrict__ counter, float* __restrict__ out)
{
    const int t  = blockIdx.x >> 2;      // 0..15 = path*8 + b
    const int sp = blockIdx.x & 3;
    const unsigned* __restrict__ base =
        (t >= 8) ? rmin + (size_t)(t - 8) * NPTS : qmin + (size_t)t * NPTS;

    float s = 0.f;
#pragma unroll
    for (int i = 0; i < 4; ++i)
        s += __uint_as_float(base[sp * 1024 + i * 256 + threadIdx.x]);

    __shared__ float red[256];
    __shared__ int amLast;
    red[threadIdx.x] = s;
    __syncthreads();
    if (threadIdx.x < 128) red[threadIdx.x] += red[threadIdx.x + 128];
    __syncthreads();
    if (threadIdx.x < 64) {
        float v = red[threadIdx.x] + red[threadIdx.x + 64];
#pragma unroll
        for (int off = 32; off > 0; off >>= 1) v += __shfl_down(v, off, 64);
        if (threadIdx.x == 0) {
            sums[blockIdx.x] = v;
            __threadfence();
            amLast = (atomicAdd(counter, 1) == 63);
        }
    }
    __syncthreads();

    if (amLast) {
        __shared__ float r16[16];
        if (threadIdx.x < 16) {
            float acc = 0.f;
#pragma unroll
            for (int k = 0; k < 4; ++k)
                acc += *(volatile const float*)&sums[threadIdx.x * 4 + k];
            r16[threadIdx.x] = sqrtf(acc / (float)NPTS);
        }
        __syncthreads();
        if (threadIdx.x == 0) {
            float p2g = 0.f, g2p = 0.f;
#pragma unroll
            for (int bb = 0; bb < NB; ++bb) { p2g += r16[bb]; g2p += r16[NB + bb]; }
            p2g *= (1.0f / NB);
            g2p *= (1.0f / NB);
            out[0] = 0.5f * (p2g + g2p);
            out[1] = p2g;
            out[2] = g2p;
            *counter = 0;   // clean for next replay
        }
    }
}

extern "C" void kernel_launch(void* const* d_in, const int* in_sizes, int n_in,
                              void* d_out, int out_size, void* d_ws, size_t ws_size,
                              hipStream_t stream) {
    const float* points = (const float*)d_in[0];
    const float* gts    = (const float*)d_in[1];
    float* out = (float*)d_out;

    unsigned* qmin = (unsigned*)d_ws;                     // NB*NPTS = 128 KB
    unsigned* rmin = qmin + (size_t)NB * NPTS;            // NB*NPTS = 128 KB
    float*    sums = (float*)(rmin + (size_t)NB * NPTS);  // 64 floats
    int*      counter = (int*)(sums + 64);

    chamfer_init<<<dim3(64), 1024, 0, stream>>>(qmin, counter);   // 64K words

    dim3 grid1(64, NB);   // (qc,rc) x batch = 512 blocks, 1024 thr, 2/CU
    chamfer_mfma32<<<grid1, 1024, 0, stream>>>(points, gts, qmin, rmin);

    chamfer_reduce2<<<dim3(64), 256, 0, stream>>>(qmin, rmin, sums, counter, out);
}

// Round 14
// 23.584 us; speedup vs baseline: 1.0021x; 1.0021x over previous
//
#include <hip/hip_runtime.h>
#include <math.h>

#define NPTS 4096
#define NB   8
#define QCB  512          // queries per block (16 waves x 32 rows)
#define RCB  512          // refs per block (16 tiles x 32)
#define NRT  16           // ref tiles per block

typedef _Float16 h8     __attribute__((ext_vector_type(8)));
typedef float    f32x16 __attribute__((ext_vector_type(16)));

__device__ __forceinline__ void split2(float v, _Float16& h, _Float16& l) {
    h = (_Float16)v;
    l = (_Float16)(v - (float)h);
}

// Init: fill qmin/rmin (2*NB*NPTS uints) with UINT_MAX, zero the counter.
__global__ __launch_bounds__(1024) void chamfer_init(unsigned* __restrict__ buf,
                                                     int* __restrict__ counter) {
    buf[blockIdx.x * 1024 + threadIdx.x] = 0xFFFFFFFFu;
    if (blockIdx.x == 0 && threadIdx.x == 0) *counter = 0;
}

// Stage 1: one block per (batch, q-chunk, r-chunk); d = pn+gn-2p.g via the
// R9-validated K=16 f16 hi/lo-split MFMA embedding (exact, absmax 0.0 x3).
// Row-min: LDS transpose, stride 34 (2-way conflicts only) + float2 reads.
// Col-min: R10-proven fminf tree + LDS int atomicMin. Both directions then
// combine globally via uint-punned atomicMin (values clamped >= 0).
__global__ __launch_bounds__(1024, 2) void chamfer_mfma32(
    const float* __restrict__ P, const float* __restrict__ G,
    unsigned* __restrict__ qmin,   // [NB][NPTS] p2g squared-NN (uint bits)
    unsigned* __restrict__ rmin)   // [NB][NPTS] g2p squared-NN
{
    __shared__ __align__(16) unsigned char smem[69632];
    h8*    Bfr  = (h8*)smem;                 // [0, 16384): 16 tiles x 64 entries
    int*   rbuf = (int*)(smem + 16384);      // [16384, 18432): 512 col-mins
    float* qtr  = (float*)smem;              // aliased in phase 3 only

    const int b    = blockIdx.y;
    const int qc   = blockIdx.x >> 3;   // 0..7
    const int rc   = blockIdx.x & 7;    // 0..7
    const int tid  = threadIdx.x;
    const int w    = tid >> 6;
    const int lane = tid & 63;
    const int col  = lane & 31;
    const int kg   = lane >> 5;

    const float* __restrict__ Pb = P + (size_t)b * NPTS * 3;
    const float* __restrict__ Gb = G + (size_t)b * NPTS * 3;

    const _Float16 one = (_Float16)1.f, zr = (_Float16)0.f;

    // ---- stage B-frags (1024 entries, 1/thread) + init rbuf
    if (tid < RCB) rbuf[tid] = 0x7f7fffff;   // FLT_MAX bits (values clamped >= 0)
    {
        const int el   = tid & 63;
        const int ecol = el & 31, ekg = el >> 5;
        const int ref  = rc * RCB + (tid >> 6) * 32 + ecol;
        const float gx = Gb[3 * ref], gy = Gb[3 * ref + 1], gz = Gb[3 * ref + 2];
        const float gn = fmaf(gx, gx, fmaf(gy, gy, gz * gz));
        _Float16 xh, xl, yh, yl, zh, zl, nh, nl;
        split2(gx, xh, xl); split2(gy, yh, yl); split2(gz, zh, zl); split2(gn, nh, nl);
        Bfr[tid] = ekg ? (h8){one, nh, xl, yl, zl, zr, nl, zr}
                       : (h8){xh, yh, zh, one, nh, xh, yh, zh};
    }

    // ---- A-frag (per lane, registers)
    const int q0 = qc * QCB + w * 32 + col;
    const float px = Pb[3 * q0], py = Pb[3 * q0 + 1], pz = Pb[3 * q0 + 2];
    const float m2x = -2.f * px, m2y = -2.f * py, m2z = -2.f * pz;
    const float pn = fmaf(px, px, fmaf(py, py, pz * pz));
    _Float16 axh, axl, ayh, ayl, azh, azl, aph, apl;
    split2(m2x, axh, axl); split2(m2y, ayh, ayl); split2(m2z, azh, azl); split2(pn, aph, apl);
    const h8 afr = kg ? (h8){apl, zr, axh, ayh, azh, aph, one, zr}
                      : (h8){axh, ayh, azh, aph, one, axl, ayl, azl};

    f32x16 qacc;
#pragma unroll
    for (int j = 0; j < 16; ++j) qacc[j] = 3.4e38f;

    __syncthreads();

    // ---- main loop: 16 MFMAs; row-min into regs, col-min tree -> LDS atomicMin
    const f32x16 cz = (f32x16){0.f,0.f,0.f,0.f,0.f,0.f,0.f,0.f,
                               0.f,0.f,0.f,0.f,0.f,0.f,0.f,0.f};
#pragma unroll
    for (int rt = 0; rt < NRT; ++rt) {
        const h8 bfr = Bfr[rt * 64 + lane];
        f32x16 d = __builtin_amdgcn_mfma_f32_32x32x16_f16(afr, bfr, cz, 0, 0, 0);
#pragma unroll
        for (int j = 0; j < 16; ++j) qacc[j] = fminf(qacc[j], d[j]);
        float t0 = fminf(fminf(d[0],  d[1]),  d[2]);
        float t1 = fminf(fminf(d[3],  d[4]),  d[5]);
        float t2 = fminf(fminf(d[6],  d[7]),  d[8]);
        float t3 = fminf(fminf(d[9],  d[10]), d[11]);
        float t4 = fminf(fminf(d[12], d[13]), d[14]);
        float v  = fminf(fminf(fminf(t0, t1), t2), fminf(fminf(t3, t4), d[15]));
        v = fmaxf(v, 0.f);
        atomicMin(&rbuf[rt * 32 + col], __float_as_int(v));
    }

    // ---- drain col-mins: 1 LDS read + 1 global atomicMin per ref
    __syncthreads();
    if (tid < RCB)
        atomicMin(&rmin[(size_t)b * NPTS + rc * RCB + tid], (unsigned)rbuf[tid]);
    __syncthreads();   // Bfr + rbuf dead; qtr may alias

    // ---- phase 3: row-min via per-wave LDS transpose, stride 34 (2-way only)
    float* qw = qtr + w * (32 * 34);           // 32 rows x 34 floats = 4352 B
#pragma unroll
    for (int j = 0; j < 16; ++j) {
        const int row = (j & 3) + 8 * (j >> 2) + 4 * kg;
        qw[row * 34 + col] = qacc[j];
    }
    // wave-private region: same wave writes then reads; lgkmcnt orders it
    if (lane < 32) {
        const float2* qr = (const float2*)(qw + lane * 34);
        float m = 3.4e38f;
#pragma unroll
        for (int k = 0; k < 16; ++k) {
            float2 u = qr[k];
            m = fminf(m, fminf(u.x, u.y));
        }
        atomicMin(&qmin[(size_t)b * NPTS + qc * QCB + w * 32 + lane],
                  __float_as_uint(fmaxf(m, 0.f)));
    }
}

// Stage 2: 64 blocks (path,b,sp); sum 1024 elems each -> sums[64];
// last block: 16 x sqrt(mean) -> 3 outputs. (R10-proven pattern.)
__global__ __launch_bounds__(256) void chamfer_reduce2(
    const unsigned* __restrict__ qmin, const unsigned* __restrict__ rmin,
    float* __restrict__ sums, int* __restrict__ counter, float* __restrict__ out)
{
    const int t  = blockIdx.x >> 2;      // 0..15 = path*8 + b
    const int sp = blockIdx.x & 3;
    const unsigned* __restrict__ base =
        (t >= 8) ? rmin + (size_t)(t - 8) * NPTS : qmin + (size_t)t * NPTS;

    float s = 0.f;
#pragma unroll
    for (int i = 0; i < 4; ++i)
        s += __uint_as_float(base[sp * 1024 + i * 256 + threadIdx.x]);

    __shared__ float red[256];
    __shared__ int amLast;
    red[threadIdx.x] = s;
    __syncthreads();
    if (threadIdx.x < 128) red[threadIdx.x] += red[threadIdx.x + 128];
    __syncthreads();
    if (threadIdx.x < 64) {
        float v = red[threadIdx.x] + red[threadIdx.x + 64];
#pragma unroll
        for (int off = 32; off > 0; off >>= 1) v += __shfl_down(v, off, 64);
        if (threadIdx.x == 0) {
            sums[blockIdx.x] = v;
            __threadfence();
            amLast = (atomicAdd(counter, 1) == 63);
        }
    }
    __syncthreads();

    if (amLast) {
        __shared__ float r16[16];
        if (threadIdx.x < 16) {
            float acc = 0.f;
#pragma unroll
            for (int k = 0; k < 4; ++k)
                acc += *(volatile const float*)&sums[threadIdx.x * 4 + k];
            r16[threadIdx.x] = sqrtf(acc / (float)NPTS);
        }
        __syncthreads();
        if (threadIdx.x == 0) {
            float p2g = 0.f, g2p = 0.f;
#pragma unroll
            for (int bb = 0; bb < NB; ++bb) { p2g += r16[bb]; g2p += r16[NB + bb]; }
            p2g *= (1.0f / NB);
            g2p *= (1.0f / NB);
            out[0] = 0.5f * (p2g + g2p);
            out[1] = p2g;
            out[2] = g2p;
            *counter = 0;   // clean for next replay
        }
    }
}

extern "C" void kernel_launch(void* const* d_in, const int* in_sizes, int n_in,
                              void* d_out, int out_size, void* d_ws, size_t ws_size,
                              hipStream_t stream) {
    const float* points = (const float*)d_in[0];
    const float* gts    = (const float*)d_in[1];
    float* out = (float*)d_out;

    unsigned* qmin = (unsigned*)d_ws;                     // NB*NPTS = 128 KB
    unsigned* rmin = qmin + (size_t)NB * NPTS;            // NB*NPTS = 128 KB
    float*    sums = (float*)(rmin + (size_t)NB * NPTS);  // 64 floats
    int*      counter = (int*)(sums + 64);

    chamfer_init<<<dim3(64), 1024, 0, stream>>>(qmin, counter);   // 64K words

    dim3 grid1(64, NB);   // (qc,rc) x batch = 512 blocks, 1024 thr, 2/CU
    chamfer_mfma32<<<grid1, 1024, 0, stream>>>(points, gts, qmin, rmin);

    chamfer_reduce2<<<dim3(64), 256, 0, stream>>>(qmin, rmin, sums, counter, out);
}

// Round 15
// 22.429 us; speedup vs baseline: 1.0537x; 1.0515x over previous
//
#include <hip/hip_runtime.h>
#include <math.h>

#define NPTS 4096
#define NB   8
#define QCB  512          // queries per block: 4 waves x 4 tiles x 32
#define RCB  1024         // refs per block: 32 tiles
#define NQC  (NPTS / QCB) // 8
#define NRC  (NPTS / RCB) // 4

typedef _Float16 h8     __attribute__((ext_vector_type(8)));
typedef float    f32x16 __attribute__((ext_vector_type(16)));

#define FOREACH_T(OP) OP(0) OP(1) OP(2) OP(3)

__device__ __forceinline__ void split2(float v, _Float16& h, _Float16& l) {
    h = (_Float16)v;
    l = (_Float16)(v - (float)h);
}

// One row-min pass per direction (grid.z): d = pn+gn-2p.g via the R9-validated
// K=16 f16 hi/lo-split MFMA embedding (exact; absmax 0.0 in R9/R10/R11/R14).
// Wave holds 4 A-frags (4 q-tiles); inner loop = 1 ds_read_b128 + 4 MFMA +
// 64 fmin  => 4x fewer LDS reads per eval than R10. No col path, no atomics.
// Epilogue: R14-proven stride-34 float2 transpose (2-way conflicts only).
__global__ __launch_bounds__(256, 2) void chamfer_mfma32(
    const float* __restrict__ P, const float* __restrict__ G,
    float* __restrict__ qpart,   // [NB][NRC][NPTS] p2g partial mins
    float* __restrict__ rpart,   // [NB][NRC][NPTS] g2p partial mins
    int* __restrict__ counter)
{
    __shared__ __align__(16) unsigned char smem[32768];
    h8*    Bfr = (h8*)smem;        // 32 tiles x 64 entries = 32 KB
    float* qtr = (float*)smem;     // aliased after loop (17408 B used)

    const int dir = blockIdx.z;
    const int b   = blockIdx.y;
    const int qc  = blockIdx.x >> 2;   // 0..7
    const int rc  = blockIdx.x & 3;    // 0..3
    const int tid = threadIdx.x;
    const int w    = tid >> 6;
    const int lane = tid & 63;
    const int col  = lane & 31;
    const int kg   = lane >> 5;

    if (blockIdx.x == 0 && b == 0 && dir == 0 && tid == 0) *counter = 0;

    const float* __restrict__ Qb = (dir ? G : P) + (size_t)b * NPTS * 3;
    const float* __restrict__ Rb = (dir ? P : G) + (size_t)b * NPTS * 3;

    const _Float16 one = (_Float16)1.f, zr = (_Float16)0.f;

    // ---- stage 1024 refs -> 2048 B-frag entries (8 per thread)
#pragma unroll
    for (int i = 0; i < 8; ++i) {
        const int e    = tid + i * 256;
        const int el   = e & 63;
        const int ecol = el & 31, ekg = el >> 5;
        const int ref  = rc * RCB + (e >> 6) * 32 + ecol;
        const float gx = Rb[3 * ref], gy = Rb[3 * ref + 1], gz = Rb[3 * ref + 2];
        const float gn = fmaf(gx, gx, fmaf(gy, gy, gz * gz));
        _Float16 xh, xl, yh, yl, zh, zl, nh, nl;
        split2(gx, xh, xl); split2(gy, yh, yl); split2(gz, zh, zl); split2(gn, nh, nl);
        Bfr[e] = ekg ? (h8){one, nh, xl, yl, zl, zr, nl, zr}
                     : (h8){xh, yh, zh, one, nh, xh, yh, zh};
    }

    // ---- 4 A-frags per wave (q-tiles w*128 + t*32), held in registers
#define DECLT(t) h8 afr##t; f32x16 qa##t;
    FOREACH_T(DECLT)
#undef DECLT
#define MKA(t) { \
        const int q0 = qc * QCB + w * 128 + (t) * 32 + col;                   \
        const float px = Qb[3 * q0], py = Qb[3 * q0 + 1], pz = Qb[3 * q0 + 2];\
        const float m2x = -2.f * px, m2y = -2.f * py, m2z = -2.f * pz;        \
        const float pn = fmaf(px, px, fmaf(py, py, pz * pz));                 \
        _Float16 xh, xl, yh, yl, zh, zl, ph, pl;                              \
        split2(m2x, xh, xl); split2(m2y, yh, yl); split2(m2z, zh, zl);        \
        split2(pn, ph, pl);                                                   \
        afr##t = kg ? (h8){pl, zr, xh, yh, zh, ph, one, zr}                   \
                    : (h8){xh, yh, zh, ph, one, xl, yl, zl};                  \
        _Pragma("unroll")                                                     \
        for (int j = 0; j < 16; ++j) qa##t[j] = 3.4e38f; }
    FOREACH_T(MKA)
#undef MKA

    __syncthreads();

    // ---- main loop: 32 ref tiles; 1 bfr read feeds 4 MFMAs
    const f32x16 cz = (f32x16){0.f,0.f,0.f,0.f,0.f,0.f,0.f,0.f,
                               0.f,0.f,0.f,0.f,0.f,0.f,0.f,0.f};
#pragma unroll 2
    for (int rt = 0; rt < 32; ++rt) {
        const h8 bfr = Bfr[rt * 64 + lane];
#define DOT(t) { \
        f32x16 d = __builtin_amdgcn_mfma_f32_32x32x16_f16(afr##t, bfr, cz, 0, 0, 0); \
        _Pragma("unroll")                                                     \
        for (int j = 0; j < 16; ++j) qa##t[j] = fminf(qa##t[j], d[j]); }
        FOREACH_T(DOT)
#undef DOT
    }

    __syncthreads();   // Bfr dead; qtr may alias

    // ---- epilogue: per-tile row-min via stride-34 LDS transpose (wave-private,
    // same-wave DS ops are FIFO-ordered; pattern validated in R14)
    float* qw = qtr + w * 1088;    // 32 rows x 34 floats per wave
    float* outb = (dir ? rpart : qpart)
                + ((size_t)b * NRC + rc) * NPTS + qc * QCB + w * 128;
#define EPI(t) { \
        _Pragma("unroll")                                                     \
        for (int j = 0; j < 16; ++j) {                                        \
            const int row = (j & 3) + 8 * (j >> 2) + 4 * kg;                  \
            qw[row * 34 + col] = qa##t[j];                                    \
        }                                                                     \
        if (lane < 32) {                                                      \
            const float2* qr = (const float2*)(qw + lane * 34);               \
            float m = 3.4e38f;                                                \
            _Pragma("unroll")                                                 \
            for (int k = 0; k < 16; ++k) {                                    \
                float2 u = qr[k];                                             \
                m = fminf(m, fminf(u.x, u.y));                                \
            }                                                                 \
            outb[(t) * 32 + lane] = fmaxf(m, 0.f);                            \
        } }
    FOREACH_T(EPI)
#undef EPI
}

// Stage 2: 64 blocks (path, b, sp); min over the 4 chunk partials per element,
// sum 1024 elems -> sums[64]; last block: 16 x sqrt(mean) -> 3 outputs.
__global__ __launch_bounds__(256) void chamfer_reduce2(
    const float* __restrict__ qpart, const float* __restrict__ rpart,
    float* __restrict__ sums, int* __restrict__ counter, float* __restrict__ out)
{
    const int t  = blockIdx.x >> 2;      // 0..15 = path*8 + b
    const int sp = blockIdx.x & 3;
    const float* __restrict__ base =
        (t >= 8 ? rpart + (size_t)(t - 8) * NRC * NPTS
                : qpart + (size_t)t * NRC * NPTS);

    float sum = 0.f;
#pragma unroll
    for (int i = 0; i < 4; ++i) {
        const int q = sp * 1024 + i * 256 + threadIdx.x;
        float mn = base[q];
#pragma unroll
        for (int c = 1; c < NRC; ++c) mn = fminf(mn, base[(size_t)c * NPTS + q]);
        sum += mn;   // already clamped >= 0 in stage 1
    }

    __shared__ float red[256];
    __shared__ int amLast;
    red[threadIdx.x] = sum;
    __syncthreads();
    if (threadIdx.x < 128) red[threadIdx.x] += red[threadIdx.x + 128];
    __syncthreads();
    if (threadIdx.x < 64) {
        float v = red[threadIdx.x] + red[threadIdx.x + 64];
#pragma unroll
        for (int off = 32; off > 0; off >>= 1) v += __shfl_down(v, off, 64);
        if (threadIdx.x == 0) {
            sums[blockIdx.x] = v;
            __threadfence();
            amLast = (atomicAdd(counter, 1) == 63);
        }
    }
    __syncthreads();

    if (amLast) {
        __shared__ float r16[16];
        if (threadIdx.x < 16) {
            float acc = 0.f;
#pragma unroll
            for (int k = 0; k < 4; ++k)
                acc += *(volatile const float*)&sums[threadIdx.x * 4 + k];
            r16[threadIdx.x] = sqrtf(acc / (float)NPTS);
        }
        __syncthreads();
        if (threadIdx.x == 0) {
            float p2g = 0.f, g2p = 0.f;
#pragma unroll
            for (int bb = 0; bb < NB; ++bb) { p2g += r16[bb]; g2p += r16[NB + bb]; }
            p2g *= (1.0f / NB);
            g2p *= (1.0f / NB);
            out[0] = 0.5f * (p2g + g2p);
            out[1] = p2g;
            out[2] = g2p;
            *counter = 0;   // clean for next replay
        }
    }
}

extern "C" void kernel_launch(void* const* d_in, const int* in_sizes, int n_in,
                              void* d_out, int out_size, void* d_ws, size_t ws_size,
                              hipStream_t stream) {
    const float* points = (const float*)d_in[0];
    const float* gts    = (const float*)d_in[1];
    float* out = (float*)d_out;

    float* qpart = (float*)d_ws;                          // NB*NRC*NPTS = 512 KB
    float* rpart = qpart + (size_t)NB * NRC * NPTS;       // 512 KB
    float* sums  = rpart + (size_t)NB * NRC * NPTS;       // 64 floats
    int*   counter = (int*)(sums + 64);

    dim3 grid1(NQC * NRC, NB, 2);   // 32 x 8 x 2 = 512 blocks, 256 thr
    chamfer_mfma32<<<grid1, 256, 0, stream>>>(points, gts, qpart, rpart, counter);

    chamfer_reduce2<<<dim3(64), 256, 0, stream>>>(qpart, rpart, sums, counter, out);
}